// Round 6
// baseline (597.121 us; speedup 1.0000x reference)
//
#include <hip/hip_runtime.h>
#include <hip/hip_bf16.h>
#include <cmath>

// Shapes (fixed for this problem)
#define B_SZ 2
#define T_SZ 2048
#define D_SZ 1024
#define F_SZ 4096
#define H_CNT 16
#define HD 64
#define NBLK 4
#define NV 5
#define MROWS (B_SZ*T_SZ)   // 4096

typedef __bf16 bf16x8 __attribute__((ext_vector_type(8)));
typedef float  f32x4  __attribute__((ext_vector_type(4)));

__device__ __forceinline__ float bf2f(unsigned short u){
  union { float f; unsigned int i; } c; c.i = ((unsigned int)u) << 16; return c.f;
}
__device__ __forceinline__ unsigned short f2bf(float f){
  union { float f; unsigned int i; } c; c.f = f;
  unsigned int x = c.i;
  return (unsigned short)((x + 0x7fffu + ((x >> 16) & 1u)) >> 16);   // RNE
}

// ---------------------------------------------------------------------------
// Weight transpose + f32->bf16: src f32 [K][N] -> dst bf16 [N][K]
// ---------------------------------------------------------------------------
__global__ __launch_bounds__(256) void transpose_f2b(
    const float* __restrict__ src, unsigned short* __restrict__ dst,
    int K, int N)
{
  __shared__ float tile[32][33];
  const int n0 = blockIdx.x * 32, k0 = blockIdx.y * 32;
  const int tx = threadIdx.x & 31, ty = threadIdx.x >> 5;   // 32 x 8
  #pragma unroll
  for (int i = 0; i < 4; i++)
    tile[ty + i*8][tx] = src[(long)(k0 + ty + i*8)*N + n0 + tx];
  __syncthreads();
  #pragma unroll
  for (int i = 0; i < 4; i++)
    dst[(long)(n0 + ty + i*8)*K + k0 + tx] = f2bf(tile[tx][ty + i*8]);
}

// ---------------------------------------------------------------------------
// block_attn_res + LayerNorm, one block per token row (b*T+t). All inputs f32.
// v = [blocks(4), extra]. Output X in bf16.
// ---------------------------------------------------------------------------
__global__ __launch_bounds__(256) void blockres_ln_kernel(
    const float* __restrict__ blocks,
    const float* __restrict__ extra,
    const float* __restrict__ res_w,
    const float* __restrict__ res_g,
    const float* __restrict__ ln_g,
    const float* __restrict__ ln_b,
    unsigned short* __restrict__ xout)
{
  const int rid = blockIdx.x;        // b*T + t
  const int tid = threadIdx.x;
  const int d0  = tid * 4;           // this thread owns d0..d0+3
  __shared__ float vs[NV][1024];     // [n][i*256+tid]
  __shared__ float rbuf[12][4];

  float wgv[4];
  {
    float4 wv = *(const float4*)(res_w + d0);
    float4 gv = *(const float4*)(res_g + d0);
    wgv[0] = wv.x*gv.x; wgv[1] = wv.y*gv.y; wgv[2] = wv.z*gv.z; wgv[3] = wv.w*gv.w;
  }

  float sq[NV], dt[NV];
  #pragma unroll
  for (int n = 0; n < NV; n++){ sq[n] = 0.f; dt[n] = 0.f; }

  #pragma unroll
  for (int n = 0; n < NV; n++){
    float4 u;
    if (n < NBLK) u = *(const float4*)(blocks + ((long)n*MROWS + rid)*D_SZ + d0);
    else          u = *(const float4*)(extra + (long)rid*D_SZ + d0);
    vs[n][0*256+tid] = u.x; vs[n][1*256+tid] = u.y;
    vs[n][2*256+tid] = u.z; vs[n][3*256+tid] = u.w;
    sq[n] += u.x*u.x + u.y*u.y + u.z*u.z + u.w*u.w;
    dt[n] += wgv[0]*u.x + wgv[1]*u.y + wgv[2]*u.z + wgv[3]*u.w;
  }

  const int wid = tid >> 6, lane = tid & 63;
  float vals[10];
  #pragma unroll
  for (int n = 0; n < NV; n++){ vals[n] = sq[n]; vals[NV+n] = dt[n]; }
  #pragma unroll
  for (int i = 0; i < 10; i++){
    float r = vals[i];
    #pragma unroll
    for (int m = 32; m >= 1; m >>= 1) r += __shfl_xor(r, m, 64);
    if (lane == 0) rbuf[i][wid] = r;
  }
  __syncthreads();

  float wsm[NV], logit[NV], mx = -1e30f;
  #pragma unroll
  for (int n = 0; n < NV; n++){
    float ssq = rbuf[n][0]+rbuf[n][1]+rbuf[n][2]+rbuf[n][3];
    float sdt = rbuf[NV+n][0]+rbuf[NV+n][1]+rbuf[NV+n][2]+rbuf[NV+n][3];
    logit[n] = sdt * rsqrtf(ssq*(1.f/D_SZ) + 1e-6f);
    mx = fmaxf(mx, logit[n]);
  }
  float se = 0.f;
  #pragma unroll
  for (int n = 0; n < NV; n++){ wsm[n] = expf(logit[n]-mx); se += wsm[n]; }
  const float inv = 1.f/se;
  #pragma unroll
  for (int n = 0; n < NV; n++) wsm[n] *= inv;

  float h[4]; float hs = 0.f, hq = 0.f;
  #pragma unroll
  for (int i = 0; i < 4; i++){
    float a = 0.f;
    #pragma unroll
    for (int n = 0; n < NV; n++) a += wsm[n]*vs[n][i*256+tid];
    h[i] = a; hs += a; hq += a*a;
  }
  #pragma unroll
  for (int m = 32; m >= 1; m >>= 1){ hs += __shfl_xor(hs, m, 64); hq += __shfl_xor(hq, m, 64); }
  if (lane == 0){ rbuf[10][wid] = hs; rbuf[11][wid] = hq; }
  __syncthreads();
  const float mean = (rbuf[10][0]+rbuf[10][1]+rbuf[10][2]+rbuf[10][3])*(1.f/D_SZ);
  const float msq  = (rbuf[11][0]+rbuf[11][1]+rbuf[11][2]+rbuf[11][3])*(1.f/D_SZ);
  const float rstd = rsqrtf(msq - mean*mean + 1e-5f);
  float4 lg = *(const float4*)(ln_g + d0);
  float4 lb = *(const float4*)(ln_b + d0);
  ushort4 ov;
  ov.x = f2bf((h[0]-mean)*rstd*lg.x + lb.x);
  ov.y = f2bf((h[1]-mean)*rstd*lg.y + lb.y);
  ov.z = f2bf((h[2]-mean)*rstd*lg.z + lb.z);
  ov.w = f2bf((h[3]-mean)*rstd*lg.w + lb.w);
  *(ushort4*)(xout + (long)rid*D_SZ + d0) = ov;
}

// ---------------------------------------------------------------------------
// bf16 GEMM: C[M][N] = A[M][K] * Bt[N][K]^T    (Bt = pre-transposed weight)
// 128x128 tile, BK=32, 4 waves (each 64x64 = 4x4 MFMA frags), mfma 16x16x32.
// EPI: 0 = store bf16 (z-batched), 1 = gelu->bf16,
//      2 = + aux(f32) -> f32 store, 3 = + aux(f32) -> f32 store (final out)
// ---------------------------------------------------------------------------
template<int EPI>
__global__ __launch_bounds__(256) void gemm_bt_kernel(
    const unsigned short* __restrict__ A,
    const unsigned short* __restrict__ Bt,
    void* __restrict__ Cv,
    const float* __restrict__ aux,
    int M, int N, int K, long sB, long sC)
{
  const int m0 = blockIdx.y * 128;
  const int n0 = blockIdx.x * 128;
  const unsigned short* Bz = Bt + (long)blockIdx.z * sB;
  const int tid = threadIdx.x;
  const int lane = tid & 63, w = tid >> 6;
  const int l15 = lane & 15, lq = lane >> 4;
  const int wr = (w >> 1) * 64, wc = (w & 1) * 64;

  __shared__ unsigned short As[128*40];   // padded stride 40 (conflict-free reads)
  __shared__ unsigned short Bs[128*40];

  f32x4 acc[4][4];
  #pragma unroll
  for (int i = 0; i < 4; i++)
    #pragma unroll
    for (int j = 0; j < 4; j++) acc[i][j] = (f32x4){0.f,0.f,0.f,0.f};

  const int srow = tid >> 2;         // 0..63
  const int scol = (tid & 3) * 8;    // 0,8,16,24

  for (int k0 = 0; k0 < K; k0 += 32){
    #pragma unroll
    for (int j = 0; j < 2; j++){
      const int r = srow + j*64;
      uint4 va = *(const uint4*)(A  + (long)(m0 + r)*K + k0 + scol);
      uint4 vb = *(const uint4*)(Bz + (long)(n0 + r)*K + k0 + scol);
      *(uint4*)(&As[r*40 + scol]) = va;
      *(uint4*)(&Bs[r*40 + scol]) = vb;
    }
    __syncthreads();
    bf16x8 af[4], bfr[4];
    #pragma unroll
    for (int i = 0; i < 4; i++) af[i]  = *(const bf16x8*)(&As[(wr + i*16 + l15)*40 + lq*8]);
    #pragma unroll
    for (int j = 0; j < 4; j++) bfr[j] = *(const bf16x8*)(&Bs[(wc + j*16 + l15)*40 + lq*8]);
    #pragma unroll
    for (int i = 0; i < 4; i++)
      #pragma unroll
      for (int j = 0; j < 4; j++)
        acc[i][j] = __builtin_amdgcn_mfma_f32_16x16x32_bf16(af[i], bfr[j], acc[i][j], 0, 0, 0);
    __syncthreads();
  }

  #pragma unroll
  for (int i = 0; i < 4; i++){
    #pragma unroll
    for (int j = 0; j < 4; j++){
      #pragma unroll
      for (int r = 0; r < 4; r++){
        const int row = m0 + wr + i*16 + lq*4 + r;
        const int col = n0 + wc + j*16 + l15;
        const long idx = (long)row*N + col;
        const float x = acc[i][j][r];
        if (EPI == 0){
          ((unsigned short*)Cv)[idx + (long)blockIdx.z*sC] = f2bf(x);
        } else if (EPI == 1){
          const float g = 0.5f*x*(1.f + tanhf(0.7978845608028654f*(x + 0.044715f*x*x*x)));
          ((unsigned short*)Cv)[idx] = f2bf(g);
        } else if (EPI == 2){
          ((float*)Cv)[idx] = aux[idx] + x;
        } else {
          ((float*)Cv)[idx] = aux[idx] + x;   // final output: f32 store (d_out is float*)
        }
      }
    }
  }
}

// ---------------------------------------------------------------------------
// RoPE in place on q and k: [B,T,H,64]; pair (d, d+32). positions = arange(T).
// cos/sin tables are f32 [T][64].
// ---------------------------------------------------------------------------
__global__ __launch_bounds__(256) void rope_kernel(
    unsigned short* __restrict__ q, unsigned short* __restrict__ k,
    const float* __restrict__ cosT, const float* __restrict__ sinT)
{
  const int i = blockIdx.x * 256 + threadIdx.x;   // over B*T*H*32
  unsigned short* p = blockIdx.y ? k : q;
  const int d = i & 31;
  const int h = (i >> 5) & (H_CNT - 1);
  const int t = (i >> 9) & (T_SZ - 1);
  const int b = i >> 20;
  const long base = ((long)(b*T_SZ + t))*D_SZ + h*HD;
  const float x1 = bf2f(p[base + d]), x2 = bf2f(p[base + d + 32]);
  const float c1 = cosT[t*HD + d],      s1 = sinT[t*HD + d];
  const float c2 = cosT[t*HD + d + 32], s2 = sinT[t*HD + d + 32];
  p[base + d]      = f2bf(x1*c1 - x2*s1);
  p[base + d + 32] = f2bf(x2*c2 + x1*s2);
}

// ---------------------------------------------------------------------------
// Causal flash attention. Grid (B*H, T/64). 4 waves x 16 q-rows, KBLK=64.
// q,k,v,o are [B,T,H*64] bf16 (head-interleaved). Scale 1/8 applied to S.
// ---------------------------------------------------------------------------
__global__ __launch_bounds__(256) void flash_attn_kernel(
    const unsigned short* __restrict__ q,
    const unsigned short* __restrict__ k,
    const unsigned short* __restrict__ v,
    unsigned short* __restrict__ o)
{
  const int bh = blockIdx.x;
  const int qt = blockIdx.y;
  const int b = bh >> 4, h = bh & 15;
  const int tid = threadIdx.x;
  const int lane = tid & 63, w = tid >> 6;
  const int l15 = lane & 15, lq = lane >> 4;

  __shared__ unsigned short Ks[64*72];    // [k_local][d], pad 72
  __shared__ unsigned short Vts[64*72];   // [d][k_local], pad 72
  __shared__ unsigned short Pl[64*72];    // [q_local][k_local], pad 72

  const long hb = (long)b*T_SZ*D_SZ + h*HD;
  const int qrow0 = qt*64 + w*16;

  bf16x8 qf[2];
  #pragma unroll
  for (int ds = 0; ds < 2; ds++)
    qf[ds] = *(const bf16x8*)(q + hb + (long)(qrow0 + l15)*D_SZ + ds*32 + lq*8);

  f32x4 acc_o[4];
  #pragma unroll
  for (int j = 0; j < 4; j++) acc_o[j] = (f32x4){0.f,0.f,0.f,0.f};
  float m_r[4] = {-1e30f,-1e30f,-1e30f,-1e30f};
  float l_r[4] = {0.f,0.f,0.f,0.f};

  const int srow = tid >> 3;         // 0..31
  const int scol = (tid & 7) * 8;    // 0..56

  for (int kt = 0; kt <= qt; kt++){
    __syncthreads();                 // prior tile fully consumed
    #pragma unroll
    for (int jj = 0; jj < 2; jj++){
      const int r = srow + jj*32;
      uint4 kw = *(const uint4*)(k + hb + (long)(kt*64 + r)*D_SZ + scol);
      *(uint4*)(&Ks[r*72 + scol]) = kw;
      uint4 vw = *(const uint4*)(v + hb + (long)(kt*64 + r)*D_SZ + scol);
      const unsigned short* vp = (const unsigned short*)&vw;
      #pragma unroll
      for (int e = 0; e < 8; e++) Vts[(scol + e)*72 + r] = vp[e];
    }
    __syncthreads();

    // S = Q K^T  (per wave: 16 q-rows x 64 k-cols)
    f32x4 sf[4];
    #pragma unroll
    for (int j = 0; j < 4; j++){
      f32x4 a = (f32x4){0.f,0.f,0.f,0.f};
      #pragma unroll
      for (int ds = 0; ds < 2; ds++){
        bf16x8 kf = *(const bf16x8*)(&Ks[(j*16 + l15)*72 + ds*32 + lq*8]);
        a = __builtin_amdgcn_mfma_f32_16x16x32_bf16(qf[ds], kf, a, 0, 0, 0);
      }
      sf[j] = a;
    }

    const bool diag = (kt == qt);
    #pragma unroll
    for (int r = 0; r < 4; r++){
      float s0 = sf[0][r]*0.125f, s1 = sf[1][r]*0.125f;
      float s2 = sf[2][r]*0.125f, s3 = sf[3][r]*0.125f;
      if (diag){
        const int qg = qrow0 + lq*4 + r;
        const int kg = kt*64 + l15;
        if (kg      > qg) s0 = -1e30f;
        if (kg + 16 > qg) s1 = -1e30f;
        if (kg + 32 > qg) s2 = -1e30f;
        if (kg + 48 > qg) s3 = -1e30f;
      }
      float mx = fmaxf(fmaxf(s0, s1), fmaxf(s2, s3));
      #pragma unroll
      for (int mk = 8; mk >= 1; mk >>= 1) mx = fmaxf(mx, __shfl_xor(mx, mk, 64));
      const float mnew  = fmaxf(m_r[r], mx);
      const float alpha = __expf(m_r[r] - mnew);
      const float p0 = __expf(s0 - mnew), p1 = __expf(s1 - mnew);
      const float p2 = __expf(s2 - mnew), p3 = __expf(s3 - mnew);
      const int prow = (w*16 + lq*4 + r)*72;
      Pl[prow +  0 + l15] = f2bf(p0);
      Pl[prow + 16 + l15] = f2bf(p1);
      Pl[prow + 32 + l15] = f2bf(p2);
      Pl[prow + 48 + l15] = f2bf(p3);
      float rs = p0 + p1 + p2 + p3;
      #pragma unroll
      for (int mk = 8; mk >= 1; mk >>= 1) rs += __shfl_xor(rs, mk, 64);
      l_r[r] = l_r[r]*alpha + rs;
      m_r[r] = mnew;
      #pragma unroll
      for (int j = 0; j < 4; j++) acc_o[j][r] *= alpha;
    }
    __syncthreads();                 // order P writes before fragment reads

    // O += P V
    bf16x8 pa[2];
    #pragma unroll
    for (int ks = 0; ks < 2; ks++)
      pa[ks] = *(const bf16x8*)(&Pl[(w*16 + l15)*72 + ks*32 + lq*8]);
    #pragma unroll
    for (int jd = 0; jd < 4; jd++){
      #pragma unroll
      for (int ks = 0; ks < 2; ks++){
        bf16x8 vf = *(const bf16x8*)(&Vts[(jd*16 + l15)*72 + ks*32 + lq*8]);
        acc_o[jd] = __builtin_amdgcn_mfma_f32_16x16x32_bf16(pa[ks], vf, acc_o[jd], 0, 0, 0);
      }
    }
  }

  float linv[4];
  #pragma unroll
  for (int r = 0; r < 4; r++) linv[r] = 1.f / l_r[r];
  #pragma unroll
  for (int jd = 0; jd < 4; jd++)
    #pragma unroll
    for (int r = 0; r < 4; r++)
      o[hb + (long)(qrow0 + lq*4 + r)*D_SZ + jd*16 + l15] = f2bf(acc_o[jd][r]*linv[r]);
}

// ---------------------------------------------------------------------------
// Launcher. Inputs f32; OUTPUT f32 (reference output dtype is float32).
// Workspace layout (MiB):
//   0   WqT/WkT/WvT/WoT bf16 (2 each)
//   8   W1T bf16 (8)
//   16  W2T bf16 (8)
//   24  X bf16 (8)
//   32  Q,K,V bf16 (8 each)   -- later reused as FF1 (32)
//   56  O bf16 (8)
//   64  partial f32 (16)       total 80 MiB
// causal_mask = tril, attention_mask = ones, positions = arange -> hardcoded.
// ---------------------------------------------------------------------------
extern "C" void kernel_launch(void* const* d_in, const int* in_sizes, int n_in,
                              void* d_out, int out_size, void* d_ws, size_t ws_size,
                              hipStream_t stream)
{
  const float* blocks     = (const float*)d_in[0];
  const float* hidden     = (const float*)d_in[1];
  const float* ln1_g      = (const float*)d_in[2];
  const float* ln1_b      = (const float*)d_in[3];
  const float* ln2_g      = (const float*)d_in[4];
  const float* ln2_b      = (const float*)d_in[5];
  const float* attn_res_w = (const float*)d_in[6];
  const float* attn_res_g = (const float*)d_in[7];
  const float* mlp_res_w  = (const float*)d_in[8];
  const float* mlp_res_g  = (const float*)d_in[9];
  const float* Wq = (const float*)d_in[10];
  const float* Wk = (const float*)d_in[11];
  const float* Wv = (const float*)d_in[12];
  const float* Wo = (const float*)d_in[13];
  const float* W1 = (const float*)d_in[14];
  const float* W2 = (const float*)d_in[15];
  const float* rope_cos = (const float*)d_in[16];
  const float* rope_sin = (const float*)d_in[17];

  char* wsb = (char*)d_ws;
  unsigned short* WTq = (unsigned short*)(wsb + (0ull  << 20));
  unsigned short* WTk = (unsigned short*)(wsb + (2ull  << 20));
  unsigned short* WTv = (unsigned short*)(wsb + (4ull  << 20));
  unsigned short* WTo = (unsigned short*)(wsb + (6ull  << 20));
  unsigned short* WT1 = (unsigned short*)(wsb + (8ull  << 20));
  unsigned short* WT2 = (unsigned short*)(wsb + (16ull << 20));
  unsigned short* Xb  = (unsigned short*)(wsb + (24ull << 20));
  unsigned short* Qb  = (unsigned short*)(wsb + (32ull << 20));
  unsigned short* Kb  = (unsigned short*)(wsb + (40ull << 20));
  unsigned short* Vb  = (unsigned short*)(wsb + (48ull << 20));
  unsigned short* Ob  = (unsigned short*)(wsb + (56ull << 20));
  unsigned short* FF1 = (unsigned short*)(wsb + (32ull << 20));   // reuse q/k/v/o
  float*          Part = (float*)(wsb + (64ull << 20));
  float*          Out  = (float*)d_out;   // f32 output

  const dim3 blk(256);

  // 1. transpose weights (f32 -> bf16, [N][K])
  transpose_f2b<<<dim3(32, 32),  blk, 0, stream>>>(Wq, WTq, 1024, 1024);
  transpose_f2b<<<dim3(32, 32),  blk, 0, stream>>>(Wk, WTk, 1024, 1024);
  transpose_f2b<<<dim3(32, 32),  blk, 0, stream>>>(Wv, WTv, 1024, 1024);
  transpose_f2b<<<dim3(32, 32),  blk, 0, stream>>>(Wo, WTo, 1024, 1024);
  transpose_f2b<<<dim3(128, 32), blk, 0, stream>>>(W1, WT1, 1024, 4096);
  transpose_f2b<<<dim3(32, 128), blk, 0, stream>>>(W2, WT2, 4096, 1024);

  // 2. block_attn_res #1 + LN1 -> X
  blockres_ln_kernel<<<dim3(MROWS), blk, 0, stream>>>(
      blocks, hidden, attn_res_w, attn_res_g, ln1_g, ln1_b, Xb);

  // 3. QKV projections (z-batched)
  gemm_bt_kernel<0><<<dim3(8, 32, 3), blk, 0, stream>>>(
      Xb, WTq, Qb, nullptr, MROWS, 1024, 1024,
      (long)1024*1024, (long)MROWS*1024);

  // 4. RoPE on Q and K
  rope_kernel<<<dim3((MROWS*H_CNT*32)/256, 2), blk, 0, stream>>>(
      Qb, Kb, rope_cos, rope_sin);

  // 5. causal flash attention -> O
  flash_attn_kernel<<<dim3(B_SZ*H_CNT, T_SZ/64), blk, 0, stream>>>(Qb, Kb, Vb, Ob);

  // 6. O @ Wo + hidden -> partial (f32)
  gemm_bt_kernel<2><<<dim3(8, 32, 1), blk, 0, stream>>>(
      Ob, WTo, Part, hidden, MROWS, 1024, 1024, 0, 0);

  // 7. block_attn_res #2 + LN2 -> X
  blockres_ln_kernel<<<dim3(MROWS), blk, 0, stream>>>(
      blocks, Part, mlp_res_w, mlp_res_g, ln2_g, ln2_b, Xb);

  // 8. X @ W1, gelu -> FF1
  gemm_bt_kernel<1><<<dim3(32, 32, 1), blk, 0, stream>>>(
      Xb, WT1, FF1, nullptr, MROWS, 4096, 1024, 0, 0);

  // 9. FF1 @ W2 + partial -> out (f32)
  gemm_bt_kernel<3><<<dim3(8, 32, 1), blk, 0, stream>>>(
      FF1, WT2, Out, Part, MROWS, 1024, 4096, 0, 0);
}